// Round 11
// baseline (341.345 us; speedup 1.0000x reference)
//
#include <hip/hip_runtime.h>
#include <stdint.h>

typedef __bf16 bf16_t;
typedef __bf16 bf16x8 __attribute__((ext_vector_type(8)));
typedef float f32x4 __attribute__((ext_vector_type(4)));
typedef unsigned short us16x8 __attribute__((ext_vector_type(8)));

#define MFMA16(a, b, c) __builtin_amdgcn_mfma_f32_16x16x32_bf16(a, b, c, 0, 0, 0)
#define BAR() __builtin_amdgcn_s_barrier()
#define PRIO1() __builtin_amdgcn_s_setprio(1)
#define PRIO0() __builtin_amdgcn_s_setprio(0)
#define LGKM0()                                        \
  do {                                                 \
    asm volatile("s_waitcnt lgkmcnt(0)" ::: "memory"); \
    __builtin_amdgcn_sched_barrier(0);                 \
  } while (0)
#define VMCNT(n)                                          \
  do {                                                    \
    asm volatile("s_waitcnt vmcnt(" #n ")" ::: "memory"); \
    __builtin_amdgcn_sched_barrier(0);                    \
  } while (0)

__device__ __forceinline__ void stage16(const bf16_t* g, bf16_t* l) {
  __builtin_amdgcn_global_load_lds((__attribute__((address_space(1))) void*)g,
                                   (__attribute__((address_space(3))) void*)l, 16, 0, 0);
}

// ---------------- f32 -> bf16 conversion ----------------
__global__ __launch_bounds__(256) void cvt_f32_to_bf16(const float* __restrict__ in,
                                                       bf16_t* __restrict__ out, int n8) {
  int i = blockIdx.x * 256 + threadIdx.x;
  if (i >= n8) return;
  const f32x4* p = (const f32x4*)(in + (size_t)i * 8);
  f32x4 a = p[0], b = p[1];
  bf16x8 o;
  o[0] = (bf16_t)a[0]; o[1] = (bf16_t)a[1]; o[2] = (bf16_t)a[2]; o[3] = (bf16_t)a[3];
  o[4] = (bf16_t)b[0]; o[5] = (bf16_t)b[1]; o[6] = (bf16_t)b[2]; o[7] = (bf16_t)b[3];
  *(bf16x8*)(out + (size_t)i * 8) = o;
}

// ====== 256x192-tile BK=32 NT GEMM, 5-DEEP buffer (latency-tolerant staging) ======
// Diagnosis (r2-r10 fit): staging is latency x concurrency limited (~600cyc service,
// only 1-phase certification slack in all prior rounds -> phase time pinned at load
// latency -> MfmaUtil 27-32% everywhere). Fix: 5 LDS buffers (140KB), stage tile t+4
// at phase t, counted wait leaves 3 batches in flight -> certification of tile t+1
// happens 3 phases after issue; in-flight ~84KB/CU -> staging can run at MFMA pace.
// Geometry (r10): 512 thr = 8 waves 2Mx4N, wave tile 128x48, acc[8][3]; grid 256
// (1 block/CU), persistent 2 tiles/block over the 512-tile space; per-XCD B-panel 3MB.
// Rotation audit: any 5 consecutive phases use 5 distinct slots; stage into
// buf[(t+4)%5] overwrites tile t-1 (reads done at phase t-1's LGKM0, before its
// end-BAR < stage issue at t). Tail dup-stages target slot (t+4)%5 which never
// collides with live tiles (index gap 4 mod 5). VMCNT(0) before epilogue/next pass.
template <int OUT_BF16>
__global__ __launch_bounds__(512, 2) void gemm_d5(const bf16_t* __restrict__ A,
                                                  const bf16_t* __restrict__ B,
                                                  const float* __restrict__ bias,
                                                  void* __restrict__ Cout,
                                                  int M, int N, int K) {
  __shared__ bf16_t SA[5 * 256 * 32];  // 5 x 8192 elems (80KB)
  __shared__ bf16_t SB[5 * 192 * 32];  // 5 x 6144 elems (60KB)
  const int tid = threadIdx.x;
  const int l = tid & 63, w = tid >> 6;
  const int l15 = l & 15, l4 = l >> 4;
  const int wm = w >> 2, wn = w & 3;  // 2M x 4N
  const bool w4 = (tid < 256);        // waves 0-3 carry the 4th staging load
  const int nk = K >> 5;              // 64

  const int r0 = tid >> 2;
  const int sc = (((tid & 3) ^ ((r0 >> 1) & 3)) << 3);
  const size_t K128 = (size_t)128 * K;

  const int swz = (l4 ^ ((l15 >> 1) & 3)) << 3;
  int aoff[8], boff[3];
#pragma unroll
  for (int i = 0; i < 8; ++i) aoff[i] = (wm * 128 + i * 16 + l15) * 32 + swz;
#pragma unroll
  for (int i = 0; i < 3; ++i) boff[i] = (wn * 48 + i * 16 + l15) * 32 + swz;

#pragma unroll 1
  for (int pass = 0; pass < 2; ++pass) {
    const int T = 64 * (blockIdx.x & 7) + (blockIdx.x >> 3) + 32 * pass;
    const int c = T >> 6, loc = T & 63;
    const int bn = 4 * c + (loc >> 4), bm = loc & 15;

    const bf16_t* gA = A + (size_t)(bm * 256 + r0) * K + sc;
    const bf16_t* gB = B + (size_t)(bn * 192 + r0) * K + sc;

    f32x4 acc[8][3] = {};

    auto STAGE = [&](int t, int buf) {
      const size_t ko = (size_t)t * 32;
      stage16(gA + ko, SA + buf * 8192 + tid * 8);
      stage16(gA + K128 + ko, SA + buf * 8192 + 4096 + tid * 8);
      stage16(gB + ko, SB + buf * 6144 + tid * 8);
      if (w4) stage16(gB + K128 + ko, SB + buf * 6144 + 4096 + tid * 8);
    };

    auto TILE = [&](int t, int bufR, int bufS) {
      const int t4 = (t + 4 < nk) ? t + 4 : nk - 1;
      STAGE(t4, bufS);
      const bf16_t* SAb = SA + bufR * 8192;
      const bf16_t* SBb = SB + bufR * 6144;
      bf16x8 aR[8], bR[3];
#pragma unroll
      for (int i = 0; i < 8; ++i) aR[i] = *(const bf16x8*)(SAb + aoff[i]);
#pragma unroll
      for (int i = 0; i < 3; ++i) bR[i] = *(const bf16x8*)(SBb + boff[i]);
      // leave 3 batches in flight; drain batch(t-3) -> tile t+1 certified at end-BAR
      if (w4) { VMCNT(12); } else { VMCNT(9); }
      BAR();
      LGKM0();
      PRIO1();
#pragma unroll
      for (int mi = 0; mi < 8; ++mi)
#pragma unroll
        for (int ni = 0; ni < 3; ++ni)
          acc[mi][ni] = MFMA16(aR[mi], bR[ni], acc[mi][ni]);
      PRIO0();
      BAR();
    };

    // prologue: stage tiles 0..3 -> bufs 0..3; drain batch0 -> tile0 certified
    STAGE(0, 0);
    STAGE(1, 1);
    STAGE(2, 2);
    STAGE(3, 3);
    if (w4) { VMCNT(12); } else { VMCNT(9); }
    BAR();

    int bR_ = 0, bS_ = 4;
#pragma unroll 1
    for (int t = 0; t < nk; ++t) {
      TILE(t, bR_, bS_);
      bR_ = (bR_ == 4) ? 0 : bR_ + 1;
      bS_ = (bS_ == 4) ? 0 : bS_ + 1;
    }
    VMCNT(0);  // drain dup-stages before epilogue / next pass's LDS reuse

    // ---- epilogue ----
    const int rbase = bm * 256 + wm * 128 + (l4 << 2);
    const int cbase = bn * 192 + wn * 48 + l15;
#pragma unroll
    for (int ni = 0; ni < 3; ++ni) {
      float bv = bias[cbase + ni * 16];
#pragma unroll
      for (int mi = 0; mi < 8; ++mi)
#pragma unroll
        for (int rr = 0; rr < 4; ++rr) {
          float v = acc[mi][ni][rr] + bv;
          size_t off = (size_t)(rbase + mi * 16 + rr) * N + (cbase + ni * 16);
          if (OUT_BF16) ((bf16_t*)Cout)[off] = (bf16_t)v;
          else ((float*)Cout)[off] = v;
        }
    }
  }
}

// ====== PERSISTENT 256x128-tile BK=32 NT GEMM (r9, proven — GEMM2) ======
template <int OUT_BF16>
__global__ __launch_bounds__(256, 2) void gemm_w128p(const bf16_t* __restrict__ A,
                                                     const bf16_t* __restrict__ B,
                                                     const float* __restrict__ bias,
                                                     void* __restrict__ Cout,
                                                     int M, int N, int K) {
  __shared__ bf16_t SA[3 * 256 * 32];
  __shared__ bf16_t SB[3 * 128 * 32];
  const int tid = threadIdx.x;
  const int l = tid & 63, w = tid >> 6;
  const int l15 = l & 15, l4 = l >> 4;
  const int wm = w >> 1, wn = w & 1;
  const int nbn = N >> 7;
  const int nbm = M >> 8;
  const int total = nbm * nbn;
  const int bnpc = nbn >> 3;

  const int r0 = tid >> 2;
  const int scol = (((tid & 3) ^ ((r0 >> 1) & 3)) << 3);
  const size_t K64 = (size_t)64 * K;

  const int swz = (l4 ^ ((l15 >> 1) & 3)) << 3;
  int aoff[8], boff[4];
#pragma unroll
  for (int i = 0; i < 8; ++i) aoff[i] = (wm * 128 + i * 16 + l15) * 32 + swz;
#pragma unroll
  for (int i = 0; i < 4; ++i) boff[i] = (wn * 64 + i * 16 + l15) * 32 + swz;

  const int nk = K >> 5;

  for (int wk = blockIdx.x; wk < total; wk += gridDim.x) {
    const int c = wk & 7, rr0 = wk >> 3;
    const int bm = rr0 / bnpc;
    const int bn = c * bnpc + rr0 % bnpc;

    const bf16_t* gA = A + (size_t)(bm * 256 + r0) * K + scol;
    const bf16_t* gB = B + (size_t)(bn * 128 + r0) * K + scol;

    f32x4 acc[8][4] = {};

    auto STAGE = [&](int t2, int buf) {
      const size_t ko = (size_t)t2 * 32;
      stage16(gA + ko, SA + buf * 8192 + tid * 8);
      stage16(gA + K64 + ko, SA + buf * 8192 + 2048 + tid * 8);
      stage16(gA + 2 * K64 + ko, SA + buf * 8192 + 4096 + tid * 8);
      stage16(gA + 3 * K64 + ko, SA + buf * 8192 + 6144 + tid * 8);
      stage16(gB + ko, SB + buf * 4096 + tid * 8);
      stage16(gB + K64 + ko, SB + buf * 4096 + 2048 + tid * 8);
    };

    auto TILE = [&](int t, int bufR, int bufS) {
      const int t2 = (t + 2 < nk) ? t + 2 : nk - 1;
      STAGE(t2, bufS);
      bf16x8 aR[8], bR[4];
#pragma unroll
      for (int i = 0; i < 8; ++i) aR[i] = *(const bf16x8*)(SA + bufR * 8192 + aoff[i]);
#pragma unroll
      for (int i = 0; i < 4; ++i) bR[i] = *(const bf16x8*)(SB + bufR * 4096 + boff[i]);
      VMCNT(6);
      BAR();
      LGKM0();
      PRIO1();
#pragma unroll
      for (int mi = 0; mi < 8; ++mi)
#pragma unroll
        for (int ni = 0; ni < 4; ++ni)
          acc[mi][ni] = MFMA16(aR[mi], bR[ni], acc[mi][ni]);
      PRIO0();
      BAR();
    };

    STAGE(0, 0);
    STAGE(1, 1);
    VMCNT(6);
    BAR();

    for (int t = 0; t < nk - 1; t += 3) {
      TILE(t, 0, 2);
      TILE(t + 1, 1, 0);
      TILE(t + 2, 2, 1);
    }
    TILE(nk - 1, 0, 2);
    VMCNT(0);

    const int rbase = bm * 256 + wm * 128 + (l4 << 2);
    const int cbase = bn * 128 + wn * 64 + l15;
#pragma unroll
    for (int ni = 0; ni < 4; ++ni) {
      float bv = bias[cbase + ni * 16];
#pragma unroll
      for (int mi = 0; mi < 8; ++mi)
#pragma unroll
        for (int rr = 0; rr < 4; ++rr) {
          float v = acc[mi][ni][rr] + bv;
          size_t off = (size_t)(rbase + mi * 16 + rr) * N + (cbase + ni * 16);
          if (OUT_BF16) ((bf16_t*)Cout)[off] = (bf16_t)v;
          else ((float*)Cout)[off] = v;
        }
    }
  }
}

// ---------------- causal flash attention (unchanged) ----------------
__global__ __launch_bounds__(256, 2) void attn_fwd(const bf16_t* __restrict__ qkv,
                                                   bf16_t* __restrict__ att) {
  __shared__ bf16_t Kt[64 * 128];
  __shared__ bf16_t Vt[128 * 64];
  __shared__ bf16_t Pw[4][16 * 64];

  int bid = blockIdx.x;
  int pair = bid >> 5, bh = bid & 31;
  int h = bh & 15, b = bh >> 4;
  int tid = threadIdx.x;
  int l = tid & 63, w = tid >> 6;
  int l15 = l & 15, l4 = l >> 4, l7 = l & 7;
  const size_t LD = 6144;
  const bf16_t* base = qkv + (size_t)b * 2048 * LD;

#pragma unroll 1
  for (int phase = 0; phase < 2; ++phase) {
    int qt = phase ? 31 - pair : pair;
    int q0 = qt << 6;
    int wq0 = q0 + w * 16;

    bf16x8 qf[4];
#pragma unroll
    for (int kk = 0; kk < 4; ++kk)
      qf[kk] = *(const bf16x8*)(base + (size_t)(wq0 + l15) * LD + h * 128 + kk * 32 + l4 * 8);

    f32x4 acc[8] = {};
    float mrow[4], lrow[4];
#pragma unroll
    for (int r = 0; r < 4; ++r) { mrow[r] = -1e30f; lrow[r] = 0.f; }

    int nkt = qt + 1;
    for (int kt = 0; kt < nkt; ++kt) {
      int kb = kt << 6;
      const bf16_t* vg = base + (size_t)kb * LD + 4096 + h * 128;
      us16x8 va[2], vb[2];
#pragma unroll
      for (int p = 0; p < 2; ++p) {
        int g = p * 256 + tid;
        int kv = (g >> 4) << 1;
        int d0 = (g & 15) << 3;
        va[p] = *(const us16x8*)(vg + (size_t)kv * LD + d0);
        vb[p] = *(const us16x8*)(vg + (size_t)(kv + 1) * LD + d0);
      }
      const bf16_t* kg = base + (size_t)kb * LD + 2048 + h * 128;
#pragma unroll
      for (int i = 0; i < 4; ++i) {
        int e = i * 256 + tid;
        int row = e >> 4, blk = e & 15;
        int src = (blk ^ (row & 7)) << 3;
        stage16(kg + (size_t)row * LD + src, Kt + e * 8);
      }
#pragma unroll
      for (int p = 0; p < 2; ++p) {
        int g = p * 256 + tid;
        int kv = (g >> 4) << 1;
        int d0 = (g & 15) << 3;
        int k8 = kv >> 3, kr = kv & 7;
#pragma unroll
        for (int j = 0; j < 8; ++j) {
          int d = d0 + j;
          int swz = k8 ^ ((d ^ (d >> 3)) & 7);
          unsigned pack = (unsigned)va[p][j] | ((unsigned)vb[p][j] << 16);
          *(unsigned*)(&Vt[d * 64 + swz * 8 + kr]) = pack;
        }
      }
      __syncthreads();

      {
        f32x4 s[4] = {};
        __builtin_amdgcn_s_setprio(1);
#pragma unroll
        for (int kk = 0; kk < 4; ++kk) {
          int blk = (kk * 4 + l4) ^ l7;
#pragma unroll
          for (int n = 0; n < 4; ++n) {
            bf16x8 kf = *(const bf16x8*)(Kt + (n * 16 + l15) * 128 + blk * 8);
            s[n] = MFMA16(qf[kk], kf, s[n]);
          }
        }
        __builtin_amdgcn_s_setprio(0);

        const float sc = 0.08838834764831845f;
        bool needMask = (kb + 63) > wq0;
        float scf[4];
#pragma unroll
        for (int r = 0; r < 4; ++r) {
          int q = wq0 + (l4 << 2) + r;
#pragma unroll
          for (int n = 0; n < 4; ++n) {
            float v = s[n][r] * sc;
            if (needMask && (kb + n * 16 + l15) > q) v = -1e30f;
            s[n][r] = v;
          }
          float mx = fmaxf(fmaxf(s[0][r], s[1][r]), fmaxf(s[2][r], s[3][r]));
          mx = fmaxf(mx, __shfl_xor(mx, 1));
          mx = fmaxf(mx, __shfl_xor(mx, 2));
          mx = fmaxf(mx, __shfl_xor(mx, 4));
          mx = fmaxf(mx, __shfl_xor(mx, 8));
          float mn = fmaxf(mrow[r], mx);
          float sf = __expf(mrow[r] - mn);
          mrow[r] = mn;
          scf[r] = sf;
          float rs = 0.f;
#pragma unroll
          for (int n = 0; n < 4; ++n) {
            float pv = __expf(s[n][r] - mn);
            s[n][r] = pv;
            rs += pv;
          }
          rs += __shfl_xor(rs, 1);
          rs += __shfl_xor(rs, 2);
          rs += __shfl_xor(rs, 4);
          rs += __shfl_xor(rs, 8);
          lrow[r] = lrow[r] * sf + rs;
        }
#pragma unroll
        for (int nd = 0; nd < 8; ++nd)
#pragma unroll
          for (int r = 0; r < 4; ++r)
            acc[nd][r] *= scf[r];
#pragma unroll
        for (int n = 0; n < 4; ++n) {
          int cb8 = n * 2 + (l15 >> 3);
#pragma unroll
          for (int r = 0; r < 4; ++r) {
            int row = (l4 << 2) + r;
            Pw[w][row * 64 + ((cb8 ^ (row & 7)) << 3) + l7] = (bf16_t)s[n][r];
          }
        }
        __builtin_amdgcn_s_setprio(1);
#pragma unroll
        for (int kk2 = 0; kk2 < 2; ++kk2) {
          bf16x8 pa = *(const bf16x8*)(&Pw[w][l15 * 64 + (((kk2 * 4 + l4) ^ l7) << 3)]);
#pragma unroll
          for (int nd = 0; nd < 8; ++nd) {
            int d = nd * 16 + l15;
            int swz = (kk2 * 4 + l4) ^ ((d ^ (d >> 3)) & 7);
            bf16x8 bv = *(const bf16x8*)(&Vt[d * 64 + swz * 8]);
            acc[nd] = MFMA16(pa, bv, acc[nd]);
          }
        }
        __builtin_amdgcn_s_setprio(0);
      }
      __syncthreads();
    }

#pragma unroll
    for (int r = 0; r < 4; ++r) {
      float inv = 1.0f / lrow[r];
      size_t ro = (size_t)(b * 2048 + wq0 + (l4 << 2) + r) * 2048 + h * 128;
#pragma unroll
      for (int nd = 0; nd < 8; ++nd)
        att[ro + nd * 16 + l15] = (bf16_t)(acc[nd][r] * inv);
    }
  }
}

// ---------------- launch ----------------
extern "C" void kernel_launch(void* const* d_in, const int* in_sizes, int n_in,
                              void* d_out, int out_size, void* d_ws, size_t ws_size,
                              hipStream_t stream) {
  (void)in_sizes; (void)n_in; (void)out_size; (void)ws_size;
  const float* x = (const float*)d_in[0];
  const float* w_attn = (const float*)d_in[1];
  const float* b_attn = (const float*)d_in[2];
  const float* w_proj = (const float*)d_in[3];
  const float* b_proj = (const float*)d_in[4];
  float* out = (float*)d_out;

  char* ws = (char*)d_ws;
  bf16_t* xb  = (bf16_t*)(ws);
  bf16_t* wab = (bf16_t*)(ws + 16777216);
  bf16_t* wpb = (bf16_t*)(ws + 41943040);
  bf16_t* qkv = (bf16_t*)(ws + 50331648);
  bf16_t* att = xb;  // xb dead after GEMM1

  cvt_f32_to_bf16<<<4096, 256, 0, stream>>>(x, xb, 1048576);
  cvt_f32_to_bf16<<<6144, 256, 0, stream>>>(w_attn, wab, 1572864);
  cvt_f32_to_bf16<<<2048, 256, 0, stream>>>(w_proj, wpb, 524288);

  // qkv = x @ w_attn^T + b_attn -> bf16 [4096, 6144]
  // 256x192 tiles, 5-deep buffering: 512 tiles = 2/block x 256 blocks, 1/CU
  gemm_d5<1><<<256, 512, 0, stream>>>(xb, wab, b_attn, qkv, 4096, 6144, 2048);

  // causal flash attention -> att bf16 [4096, 2048]
  attn_fwd<<<512, 256, 0, stream>>>(qkv, att);

  // out = att @ w_proj^T + b_proj -> f32 [4096, 2048]  (256x128 persistent, proven)
  gemm_w128p<0><<<512, 256, 0, stream>>>(att, wpb, b_proj, out, 4096, 2048, 2048);
}

// Round 12
// 304.795 us; speedup vs baseline: 1.1199x; 1.1199x over previous
//
#include <hip/hip_runtime.h>
#include <stdint.h>

typedef __bf16 bf16_t;
typedef __bf16 bf16x8 __attribute__((ext_vector_type(8)));
typedef float f32x4 __attribute__((ext_vector_type(4)));
typedef unsigned short us16x8 __attribute__((ext_vector_type(8)));

#define MFMA16(a, b, c) __builtin_amdgcn_mfma_f32_16x16x32_bf16(a, b, c, 0, 0, 0)
#define BAR() __builtin_amdgcn_s_barrier()
#define PRIO1() __builtin_amdgcn_s_setprio(1)
#define PRIO0() __builtin_amdgcn_s_setprio(0)
#define LGKM0()                                        \
  do {                                                 \
    asm volatile("s_waitcnt lgkmcnt(0)" ::: "memory"); \
    __builtin_amdgcn_sched_barrier(0);                 \
  } while (0)
#define VMCNT(n)                                          \
  do {                                                    \
    asm volatile("s_waitcnt vmcnt(" #n ")" ::: "memory"); \
    __builtin_amdgcn_sched_barrier(0);                    \
  } while (0)

__device__ __forceinline__ void stage16(const bf16_t* g, bf16_t* l) {
  __builtin_amdgcn_global_load_lds((__attribute__((address_space(1))) void*)g,
                                   (__attribute__((address_space(3))) void*)l, 16, 0, 0);
}

// ---------------- f32 -> bf16 conversion ----------------
__global__ __launch_bounds__(256) void cvt_f32_to_bf16(const float* __restrict__ in,
                                                       bf16_t* __restrict__ out, int n8) {
  int i = blockIdx.x * 256 + threadIdx.x;
  if (i >= n8) return;
  const f32x4* p = (const f32x4*)(in + (size_t)i * 8);
  f32x4 a = p[0], b = p[1];
  bf16x8 o;
  o[0] = (bf16_t)a[0]; o[1] = (bf16_t)a[1]; o[2] = (bf16_t)a[2]; o[3] = (bf16_t)a[3];
  o[4] = (bf16_t)b[0]; o[5] = (bf16_t)b[1]; o[6] = (bf16_t)b[2]; o[7] = (bf16_t)b[3];
  *(bf16x8*)(out + (size_t)i * 8) = o;
}

// ====== 256x128-tile BK=32 NT GEMM, 4-phase QUADRANT schedule, persistent, 2/CU ======
// Synthesis of 11 rounds: fine-grained quadrant phases (r4's structure, 44% intrinsic
// MfmaUtil vs 30-35% for monolithic phases) + 2-block/CU streaming persistence (r9).
// 256 thr = 4 waves 2Mx2N, wave tile 128x64, acc[8][4]. LDS: SA[2][256][32] +
// SB[2][128][32] = 48 KB -> 2 blocks/CU. Per K-tile(32), 4 phases of 8 MFMA:
//  Ph1: read aLo(4)+bLo(2)           -> MFMA acc[0..3][0..1]
//  Ph2: read bHi(2)                  -> MFMA acc[0..3][2..3]
//  Ph3: read aHi(4); stage B(t+2)    -> MFMA acc[4..7][2..3]   (B dead after Ph2)
//  Ph4: stage A(t+2); VMCNT(6)       -> MFMA acc[4..7][0..1]   (A dead after Ph3;
//       bLo/aHi from regs — no LDS reads, no LGKM needed)
// vmcnt audit (per thread: A=4, B=2 loads/tile): at t.Ph4 outstanding = t+1's 6 +
// t+2's 6 = 12; VMCNT(6) certifies tile t+1 before its Ph1 (issued t-1.Ph3/Ph4 ->
// ~4 sub-phases of slack). Prologue (t0,t1 staged, VMCNT(6)) = same steady state.
// Tail dup-stages (t2 clamped) overwrite dead regions with identical bytes; VMCNT(0)
// before epilogue. Swizzle: r7-r9-verified 0-conflict pattern (pre-swizzled global
// source + swizzled ds_read). Grid 512 persistent over 768 tiles, XCD-chunked.
template <int OUT_BF16>
__global__ __launch_bounds__(256, 2) void gemm_q4(const bf16_t* __restrict__ A,
                                                  const bf16_t* __restrict__ B,
                                                  const float* __restrict__ bias,
                                                  void* __restrict__ Cout,
                                                  int M, int N, int K) {
  __shared__ bf16_t SA[2 * 256 * 32];
  __shared__ bf16_t SB[2 * 128 * 32];
  const int tid = threadIdx.x;
  const int l = tid & 63, w = tid >> 6;
  const int l15 = l & 15, l4 = l >> 4;
  const int wm = w >> 1, wn = w & 1;
  const int nbn = N >> 7;
  const int nbm = M >> 8;
  const int total = nbm * nbn;
  const int bnpc = nbn >> 3;

  const int r0 = tid >> 2;
  const int scol = (((tid & 3) ^ ((r0 >> 1) & 3)) << 3);
  const size_t K64 = (size_t)64 * K;

  const int swz = (l4 ^ ((l15 >> 1) & 3)) << 3;
  int aoff[8], boff[4];
#pragma unroll
  for (int i = 0; i < 8; ++i) aoff[i] = (wm * 128 + i * 16 + l15) * 32 + swz;
#pragma unroll
  for (int i = 0; i < 4; ++i) boff[i] = (wn * 64 + i * 16 + l15) * 32 + swz;

  const int nk = K >> 5;  // 64 (even)

  for (int wk = blockIdx.x; wk < total; wk += gridDim.x) {
    const int c = wk & 7, rr = wk >> 3;
    const int bm = rr / bnpc;
    const int bn = c * bnpc + rr % bnpc;

    const bf16_t* gA = A + (size_t)(bm * 256 + r0) * K + scol;
    const bf16_t* gB = B + (size_t)(bn * 128 + r0) * K + scol;

    f32x4 acc[8][4] = {};

    auto STA = [&](int t, int buf) {
      const size_t ko = (size_t)t * 32;
      stage16(gA + ko, SA + buf * 8192 + tid * 8);
      stage16(gA + K64 + ko, SA + buf * 8192 + 2048 + tid * 8);
      stage16(gA + 2 * K64 + ko, SA + buf * 8192 + 4096 + tid * 8);
      stage16(gA + 3 * K64 + ko, SA + buf * 8192 + 6144 + tid * 8);
    };
    auto STB = [&](int t, int buf) {
      const size_t ko = (size_t)t * 32;
      stage16(gB + ko, SB + buf * 4096 + tid * 8);
      stage16(gB + K64 + ko, SB + buf * 4096 + 2048 + tid * 8);
    };

    auto TILE = [&](int t, int cur) {
      const int t2 = (t + 2 < nk) ? t + 2 : nk - 1;
      const bf16_t* SAb = SA + cur * 8192;
      const bf16_t* SBb = SB + cur * 4096;
      bf16x8 aR[4], bLo[2], bHi[2];
      // ---- Ph1: aLo + bLo -> MloNlo ----
#pragma unroll
      for (int i = 0; i < 4; ++i) aR[i] = *(const bf16x8*)(SAb + aoff[i]);
      bLo[0] = *(const bf16x8*)(SBb + boff[0]);
      bLo[1] = *(const bf16x8*)(SBb + boff[1]);
      BAR();
      LGKM0();
      PRIO1();
#pragma unroll
      for (int mi = 0; mi < 4; ++mi) {
        acc[mi][0] = MFMA16(aR[mi], bLo[0], acc[mi][0]);
        acc[mi][1] = MFMA16(aR[mi], bLo[1], acc[mi][1]);
      }
      PRIO0();
      BAR();
      // ---- Ph2: bHi -> MloNhi ----
      bHi[0] = *(const bf16x8*)(SBb + boff[2]);
      bHi[1] = *(const bf16x8*)(SBb + boff[3]);
      BAR();
      LGKM0();
      PRIO1();
#pragma unroll
      for (int mi = 0; mi < 4; ++mi) {
        acc[mi][2] = MFMA16(aR[mi], bHi[0], acc[mi][2]);
        acc[mi][3] = MFMA16(aR[mi], bHi[1], acc[mi][3]);
      }
      PRIO0();
      BAR();
      // ---- Ph3: aHi (reuse aR); stage B(t+2) into cur (B dead after Ph2) ----
#pragma unroll
      for (int i = 0; i < 4; ++i) aR[i] = *(const bf16x8*)(SAb + aoff[4 + i]);
      STB(t2, cur);
      BAR();
      LGKM0();
      PRIO1();
#pragma unroll
      for (int mi = 0; mi < 4; ++mi) {
        acc[4 + mi][2] = MFMA16(aR[mi], bHi[0], acc[4 + mi][2]);
        acc[4 + mi][3] = MFMA16(aR[mi], bHi[1], acc[4 + mi][3]);
      }
      PRIO0();
      BAR();
      // ---- Ph4: stage A(t+2) (A dead after Ph3); counted VMCNT; regs-only MFMA ----
      STA(t2, cur);
      VMCNT(6);
      BAR();
      PRIO1();
#pragma unroll
      for (int mi = 0; mi < 4; ++mi) {
        acc[4 + mi][0] = MFMA16(aR[mi], bLo[0], acc[4 + mi][0]);
        acc[4 + mi][1] = MFMA16(aR[mi], bLo[1], acc[4 + mi][1]);
      }
      PRIO0();
      BAR();
    };

    // prologue: tiles 0,1 -> bufs 0,1; VMCNT(6) certifies tile0
    STA(0, 0);
    STB(0, 0);
    STA(1, 1);
    STB(1, 1);
    VMCNT(6);
    BAR();

#pragma unroll 1
    for (int t = 0; t < nk; t += 2) {
      TILE(t, 0);
      TILE(t + 1, 1);
    }
    VMCNT(0);  // drain dup-stages before epilogue / next tile's LDS reuse

    // ---- epilogue ----
    const int rbase = bm * 256 + wm * 128 + (l4 << 2);
    const int cbase = bn * 128 + wn * 64 + l15;
#pragma unroll
    for (int ni = 0; ni < 4; ++ni) {
      float bv = bias[cbase + ni * 16];
#pragma unroll
      for (int mi = 0; mi < 8; ++mi)
#pragma unroll
        for (int rx = 0; rx < 4; ++rx) {
          float v = acc[mi][ni][rx] + bv;
          size_t off = (size_t)(rbase + mi * 16 + rx) * N + (cbase + ni * 16);
          if (OUT_BF16) ((bf16_t*)Cout)[off] = (bf16_t)v;
          else ((float*)Cout)[off] = v;
        }
    }
  }
}

// ---------------- causal flash attention (unchanged) ----------------
__global__ __launch_bounds__(256, 2) void attn_fwd(const bf16_t* __restrict__ qkv,
                                                   bf16_t* __restrict__ att) {
  __shared__ bf16_t Kt[64 * 128];
  __shared__ bf16_t Vt[128 * 64];
  __shared__ bf16_t Pw[4][16 * 64];

  int bid = blockIdx.x;
  int pair = bid >> 5, bh = bid & 31;
  int h = bh & 15, b = bh >> 4;
  int tid = threadIdx.x;
  int l = tid & 63, w = tid >> 6;
  int l15 = l & 15, l4 = l >> 4, l7 = l & 7;
  const size_t LD = 6144;
  const bf16_t* base = qkv + (size_t)b * 2048 * LD;

#pragma unroll 1
  for (int phase = 0; phase < 2; ++phase) {
    int qt = phase ? 31 - pair : pair;
    int q0 = qt << 6;
    int wq0 = q0 + w * 16;

    bf16x8 qf[4];
#pragma unroll
    for (int kk = 0; kk < 4; ++kk)
      qf[kk] = *(const bf16x8*)(base + (size_t)(wq0 + l15) * LD + h * 128 + kk * 32 + l4 * 8);

    f32x4 acc[8] = {};
    float mrow[4], lrow[4];
#pragma unroll
    for (int r = 0; r < 4; ++r) { mrow[r] = -1e30f; lrow[r] = 0.f; }

    int nkt = qt + 1;
    for (int kt = 0; kt < nkt; ++kt) {
      int kb = kt << 6;
      const bf16_t* vg = base + (size_t)kb * LD + 4096 + h * 128;
      us16x8 va[2], vb[2];
#pragma unroll
      for (int p = 0; p < 2; ++p) {
        int g = p * 256 + tid;
        int kv = (g >> 4) << 1;
        int d0 = (g & 15) << 3;
        va[p] = *(const us16x8*)(vg + (size_t)kv * LD + d0);
        vb[p] = *(const us16x8*)(vg + (size_t)(kv + 1) * LD + d0);
      }
      const bf16_t* kg = base + (size_t)kb * LD + 2048 + h * 128;
#pragma unroll
      for (int i = 0; i < 4; ++i) {
        int e = i * 256 + tid;
        int row = e >> 4, blk = e & 15;
        int src = (blk ^ (row & 7)) << 3;
        stage16(kg + (size_t)row * LD + src, Kt + e * 8);
      }
#pragma unroll
      for (int p = 0; p < 2; ++p) {
        int g = p * 256 + tid;
        int kv = (g >> 4) << 1;
        int d0 = (g & 15) << 3;
        int k8 = kv >> 3, kr = kv & 7;
#pragma unroll
        for (int j = 0; j < 8; ++j) {
          int d = d0 + j;
          int swz = k8 ^ ((d ^ (d >> 3)) & 7);
          unsigned pack = (unsigned)va[p][j] | ((unsigned)vb[p][j] << 16);
          *(unsigned*)(&Vt[d * 64 + swz * 8 + kr]) = pack;
        }
      }
      __syncthreads();

      {
        f32x4 s[4] = {};
        __builtin_amdgcn_s_setprio(1);
#pragma unroll
        for (int kk = 0; kk < 4; ++kk) {
          int blk = (kk * 4 + l4) ^ l7;
#pragma unroll
          for (int n = 0; n < 4; ++n) {
            bf16x8 kf = *(const bf16x8*)(Kt + (n * 16 + l15) * 128 + blk * 8);
            s[n] = MFMA16(qf[kk], kf, s[n]);
          }
        }
        __builtin_amdgcn_s_setprio(0);

        const float sc = 0.08838834764831845f;
        bool needMask = (kb + 63) > wq0;
        float scf[4];
#pragma unroll
        for (int r = 0; r < 4; ++r) {
          int q = wq0 + (l4 << 2) + r;
#pragma unroll
          for (int n = 0; n < 4; ++n) {
            float v = s[n][r] * sc;
            if (needMask && (kb + n * 16 + l15) > q) v = -1e30f;
            s[n][r] = v;
          }
          float mx = fmaxf(fmaxf(s[0][r], s[1][r]), fmaxf(s[2][r], s[3][r]));
          mx = fmaxf(mx, __shfl_xor(mx, 1));
          mx = fmaxf(mx, __shfl_xor(mx, 2));
          mx = fmaxf(mx, __shfl_xor(mx, 4));
          mx = fmaxf(mx, __shfl_xor(mx, 8));
          float mn = fmaxf(mrow[r], mx);
          float sf = __expf(mrow[r] - mn);
          mrow[r] = mn;
          scf[r] = sf;
          float rs = 0.f;
#pragma unroll
          for (int n = 0; n < 4; ++n) {
            float pv = __expf(s[n][r] - mn);
            s[n][r] = pv;
            rs += pv;
          }
          rs += __shfl_xor(rs, 1);
          rs += __shfl_xor(rs, 2);
          rs += __shfl_xor(rs, 4);
          rs += __shfl_xor(rs, 8);
          lrow[r] = lrow[r] * sf + rs;
        }
#pragma unroll
        for (int nd = 0; nd < 8; ++nd)
#pragma unroll
          for (int r = 0; r < 4; ++r)
            acc[nd][r] *= scf[r];
#pragma unroll
        for (int n = 0; n < 4; ++n) {
          int cb8 = n * 2 + (l15 >> 3);
#pragma unroll
          for (int r = 0; r < 4; ++r) {
            int row = (l4 << 2) + r;
            Pw[w][row * 64 + ((cb8 ^ (row & 7)) << 3) + l7] = (bf16_t)s[n][r];
          }
        }
        __builtin_amdgcn_s_setprio(1);
#pragma unroll
        for (int kk2 = 0; kk2 < 2; ++kk2) {
          bf16x8 pa = *(const bf16x8*)(&Pw[w][l15 * 64 + (((kk2 * 4 + l4) ^ l7) << 3)]);
#pragma unroll
          for (int nd = 0; nd < 8; ++nd) {
            int d = nd * 16 + l15;
            int swz = (kk2 * 4 + l4) ^ ((d ^ (d >> 3)) & 7);
            bf16x8 bv = *(const bf16x8*)(&Vt[d * 64 + swz * 8]);
            acc[nd] = MFMA16(pa, bv, acc[nd]);
          }
        }
        __builtin_amdgcn_s_setprio(0);
      }
      __syncthreads();
    }

#pragma unroll
    for (int r = 0; r < 4; ++r) {
      float inv = 1.0f / lrow[r];
      size_t ro = (size_t)(b * 2048 + wq0 + (l4 << 2) + r) * 2048 + h * 128;
#pragma unroll
      for (int nd = 0; nd < 8; ++nd)
        att[ro + nd * 16 + l15] = (bf16_t)(acc[nd][r] * inv);
    }
  }
}

// ---------------- launch ----------------
extern "C" void kernel_launch(void* const* d_in, const int* in_sizes, int n_in,
                              void* d_out, int out_size, void* d_ws, size_t ws_size,
                              hipStream_t stream) {
  (void)in_sizes; (void)n_in; (void)out_size; (void)ws_size;
  const float* x = (const float*)d_in[0];
  const float* w_attn = (const float*)d_in[1];
  const float* b_attn = (const float*)d_in[2];
  const float* w_proj = (const float*)d_in[3];
  const float* b_proj = (const float*)d_in[4];
  float* out = (float*)d_out;

  char* ws = (char*)d_ws;
  bf16_t* xb  = (bf16_t*)(ws);
  bf16_t* wab = (bf16_t*)(ws + 16777216);
  bf16_t* wpb = (bf16_t*)(ws + 41943040);
  bf16_t* qkv = (bf16_t*)(ws + 50331648);
  bf16_t* att = xb;  // xb dead after GEMM1

  cvt_f32_to_bf16<<<4096, 256, 0, stream>>>(x, xb, 1048576);
  cvt_f32_to_bf16<<<6144, 256, 0, stream>>>(w_attn, wab, 1572864);
  cvt_f32_to_bf16<<<2048, 256, 0, stream>>>(w_proj, wpb, 524288);

  // qkv = x @ w_attn^T + b_attn -> bf16 [4096, 6144]
  // 256x128 tiles, 4-phase quadrant schedule, persistent grid 512 (2/CU) over 768
  gemm_q4<1><<<512, 256, 0, stream>>>(xb, wab, b_attn, qkv, 4096, 6144, 2048);

  // causal flash attention -> att bf16 [4096, 2048]
  attn_fwd<<<512, 256, 0, stream>>>(qkv, att);

  // out = att @ w_proj^T + b_proj -> f32 [4096, 2048]  (same structure, 512 tiles)
  gemm_q4<0><<<512, 256, 0, stream>>>(att, wpb, b_proj, out, 4096, 2048, 2048);
}

// Round 13
// 296.906 us; speedup vs baseline: 1.1497x; 1.0266x over previous
//
#include <hip/hip_runtime.h>
#include <stdint.h>

typedef __bf16 bf16_t;
typedef __bf16 bf16x8 __attribute__((ext_vector_type(8)));
typedef float f32x4 __attribute__((ext_vector_type(4)));
typedef unsigned short us16x8 __attribute__((ext_vector_type(8)));

#define MFMA16(a, b, c) __builtin_amdgcn_mfma_f32_16x16x32_bf16(a, b, c, 0, 0, 0)
#define BAR() __builtin_amdgcn_s_barrier()
#define PRIO1() __builtin_amdgcn_s_setprio(1)
#define PRIO0() __builtin_amdgcn_s_setprio(0)
#define LGKM0()                                        \
  do {                                                 \
    asm volatile("s_waitcnt lgkmcnt(0)" ::: "memory"); \
    __builtin_amdgcn_sched_barrier(0);                 \
  } while (0)
#define VMCNT(n)                                          \
  do {                                                    \
    asm volatile("s_waitcnt vmcnt(" #n ")" ::: "memory"); \
    __builtin_amdgcn_sched_barrier(0);                    \
  } while (0)

__device__ __forceinline__ void stage16(const bf16_t* g, bf16_t* l) {
  __builtin_amdgcn_global_load_lds((__attribute__((address_space(1))) void*)g,
                                   (__attribute__((address_space(3))) void*)l, 16, 0, 0);
}

// ---------------- fused f32 -> bf16 conversion (x, w_attn, w_proj) ----------------
// Region sizes in vec8 units: x 1,048,576 | w_attn 1,572,864 | w_proj 524,288.
// All boundaries divide 256 -> no intra-block divergence.
__global__ __launch_bounds__(256) void cvt_all(const float* __restrict__ x,
                                               const float* __restrict__ wa,
                                               const float* __restrict__ wp,
                                               bf16_t* __restrict__ xb,
                                               bf16_t* __restrict__ wab,
                                               bf16_t* __restrict__ wpb) {
  int i = blockIdx.x * 256 + threadIdx.x;
  const float* src;
  bf16_t* dst;
  if (i < 1048576) {
    src = x + (size_t)i * 8;
    dst = xb + (size_t)i * 8;
  } else if (i < 2621440) {
    size_t j = (size_t)(i - 1048576) * 8;
    src = wa + j;
    dst = wab + j;
  } else {
    size_t j = (size_t)(i - 2621440) * 8;
    src = wp + j;
    dst = wpb + j;
  }
  const f32x4* p = (const f32x4*)src;
  f32x4 a = p[0], b = p[1];
  bf16x8 o;
  o[0] = (bf16_t)a[0]; o[1] = (bf16_t)a[1]; o[2] = (bf16_t)a[2]; o[3] = (bf16_t)a[3];
  o[4] = (bf16_t)b[0]; o[5] = (bf16_t)b[1]; o[6] = (bf16_t)b[2]; o[7] = (bf16_t)b[3];
  *(bf16x8*)dst = o;
}

// ====== PERSISTENT 256x128-tile BK=32 NT GEMM (r9 exact, best measured) ======
template <int OUT_BF16>
__global__ __launch_bounds__(256, 2) void gemm_w128p(const bf16_t* __restrict__ A,
                                                     const bf16_t* __restrict__ B,
                                                     const float* __restrict__ bias,
                                                     void* __restrict__ Cout,
                                                     int M, int N, int K) {
  __shared__ bf16_t SA[3 * 256 * 32];
  __shared__ bf16_t SB[3 * 128 * 32];
  const int tid = threadIdx.x;
  const int l = tid & 63, w = tid >> 6;
  const int l15 = l & 15, l4 = l >> 4;
  const int wm = w >> 1, wn = w & 1;
  const int nbn = N >> 7;
  const int nbm = M >> 8;
  const int total = nbm * nbn;
  const int bnpc = nbn >> 3;

  const int r0 = tid >> 2;
  const int scol = (((tid & 3) ^ ((r0 >> 1) & 3)) << 3);
  const size_t K64 = (size_t)64 * K;

  const int swz = (l4 ^ ((l15 >> 1) & 3)) << 3;
  int aoff[8], boff[4];
#pragma unroll
  for (int i = 0; i < 8; ++i) aoff[i] = (wm * 128 + i * 16 + l15) * 32 + swz;
#pragma unroll
  for (int i = 0; i < 4; ++i) boff[i] = (wn * 64 + i * 16 + l15) * 32 + swz;

  const int nk = K >> 5;

  for (int wk = blockIdx.x; wk < total; wk += gridDim.x) {
    const int c = wk & 7, rr0 = wk >> 3;
    const int bm = rr0 / bnpc;
    const int bn = c * bnpc + rr0 % bnpc;

    const bf16_t* gA = A + (size_t)(bm * 256 + r0) * K + scol;
    const bf16_t* gB = B + (size_t)(bn * 128 + r0) * K + scol;

    f32x4 acc[8][4] = {};

    auto STAGE = [&](int t2, int buf) {
      const size_t ko = (size_t)t2 * 32;
      stage16(gA + ko, SA + buf * 8192 + tid * 8);
      stage16(gA + K64 + ko, SA + buf * 8192 + 2048 + tid * 8);
      stage16(gA + 2 * K64 + ko, SA + buf * 8192 + 4096 + tid * 8);
      stage16(gA + 3 * K64 + ko, SA + buf * 8192 + 6144 + tid * 8);
      stage16(gB + ko, SB + buf * 4096 + tid * 8);
      stage16(gB + K64 + ko, SB + buf * 4096 + 2048 + tid * 8);
    };

    auto TILE = [&](int t, int bufR, int bufS) {
      const int t2 = (t + 2 < nk) ? t + 2 : nk - 1;
      STAGE(t2, bufS);
      bf16x8 aR[8], bR[4];
#pragma unroll
      for (int i = 0; i < 8; ++i) aR[i] = *(const bf16x8*)(SA + bufR * 8192 + aoff[i]);
#pragma unroll
      for (int i = 0; i < 4; ++i) bR[i] = *(const bf16x8*)(SB + bufR * 4096 + boff[i]);
      VMCNT(6);
      BAR();
      LGKM0();
      PRIO1();
#pragma unroll
      for (int mi = 0; mi < 8; ++mi)
#pragma unroll
        for (int ni = 0; ni < 4; ++ni)
          acc[mi][ni] = MFMA16(aR[mi], bR[ni], acc[mi][ni]);
      PRIO0();
      BAR();
    };

    STAGE(0, 0);
    STAGE(1, 1);
    VMCNT(6);
    BAR();

    for (int t = 0; t < nk - 1; t += 3) {
      TILE(t, 0, 2);
      TILE(t + 1, 1, 0);
      TILE(t + 2, 2, 1);
    }
    TILE(nk - 1, 0, 2);
    VMCNT(0);

    const int rbase = bm * 256 + wm * 128 + (l4 << 2);
    const int cbase = bn * 128 + wn * 64 + l15;
#pragma unroll
    for (int ni = 0; ni < 4; ++ni) {
      float bv = bias[cbase + ni * 16];
#pragma unroll
      for (int mi = 0; mi < 8; ++mi)
#pragma unroll
        for (int rr = 0; rr < 4; ++rr) {
          float v = acc[mi][ni][rr] + bv;
          size_t off = (size_t)(rbase + mi * 16 + rr) * N + (cbase + ni * 16);
          if (OUT_BF16) ((bf16_t*)Cout)[off] = (bf16_t)v;
          else ((float*)Cout)[off] = v;
        }
    }
  }
}

// ---------------- causal flash attention, K/V DOUBLE-BUFFERED (T14) ----------------
// Per step t: issue V(t+1) reg-loads (4 vm) then K(t+1) global_load_lds (4 vm) into
// buf^1 BEFORE QK^T; after softmax VMCNT(4) (V done, K flying) + ds_write V(t+1);
// PV on buf; end LGKM0 + VMCNT(0) + BAR (K wait sits ~1500cyc after issue: hidden).
// Buffer audit: buf[nxt]'s last reads (step t-1) complete before t-1's end-BAR <
// step t's writes. Pw per-wave. LDS 72KB -> 2 blocks/CU.
__global__ __launch_bounds__(256, 2) void attn_fwd(const bf16_t* __restrict__ qkv,
                                                   bf16_t* __restrict__ att) {
  __shared__ bf16_t Kt[2][64 * 128];
  __shared__ bf16_t Vt[2][128 * 64];
  __shared__ bf16_t Pw[4][16 * 64];

  int bid = blockIdx.x;
  int pair = bid >> 5, bh = bid & 31;
  int h = bh & 15, b = bh >> 4;
  int tid = threadIdx.x;
  int l = tid & 63, w = tid >> 6;
  int l15 = l & 15, l4 = l >> 4, l7 = l & 7;
  const size_t LD = 6144;
  const bf16_t* base = qkv + (size_t)b * 2048 * LD;

  us16x8 va[2], vb[2];

  auto loadV = [&](int kb) {
    const bf16_t* vg = base + (size_t)kb * LD + 4096 + h * 128;
#pragma unroll
    for (int p = 0; p < 2; ++p) {
      int g = p * 256 + tid;
      int kvp = (g >> 4) << 1;
      int d0 = (g & 15) << 3;
      va[p] = *(const us16x8*)(vg + (size_t)kvp * LD + d0);
      vb[p] = *(const us16x8*)(vg + (size_t)(kvp + 1) * LD + d0);
    }
  };
  auto stageK = [&](int kb, int buf) {
    const bf16_t* kg = base + (size_t)kb * LD + 2048 + h * 128;
#pragma unroll
    for (int i = 0; i < 4; ++i) {
      int e = i * 256 + tid;
      int row = e >> 4, blk = e & 15;
      int src = (blk ^ (row & 7)) << 3;
      stage16(kg + (size_t)row * LD + src, &Kt[buf][e * 8]);
    }
  };
  auto writeV = [&](int buf) {
#pragma unroll
    for (int p = 0; p < 2; ++p) {
      int g = p * 256 + tid;
      int kvp = (g >> 4) << 1;
      int d0 = (g & 15) << 3;
      int k8 = kvp >> 3, kr = kvp & 7;
#pragma unroll
      for (int j = 0; j < 8; ++j) {
        int d = d0 + j;
        int swzv = k8 ^ ((d ^ (d >> 3)) & 7);
        unsigned pack = (unsigned)va[p][j] | ((unsigned)vb[p][j] << 16);
        *(unsigned*)(&Vt[buf][d * 64 + swzv * 8 + kr]) = pack;
      }
    }
  };

#pragma unroll 1
  for (int phase = 0; phase < 2; ++phase) {
    int qt = phase ? 31 - pair : pair;
    int q0 = qt << 6;
    int wq0 = q0 + w * 16;

    bf16x8 qf[4];
#pragma unroll
    for (int kk = 0; kk < 4; ++kk)
      qf[kk] = *(const bf16x8*)(base + (size_t)(wq0 + l15) * LD + h * 128 + kk * 32 + l4 * 8);

    f32x4 acc[8] = {};
    float mrow[4], lrow[4];
#pragma unroll
    for (int r = 0; r < 4; ++r) { mrow[r] = -1e30f; lrow[r] = 0.f; }

    int nkt = qt + 1;

    // ---- prologue: V0 loads (oldest), K0 stage; VMCNT(4) -> V0 done; write V0 ----
    loadV(0);
    stageK(0, 0);
    VMCNT(4);
    writeV(0);
    LGKM0();
    VMCNT(0);
    BAR();

#pragma unroll 1
    for (int kt = 0; kt < nkt; ++kt) {
      const int cur = kt & 1, nxt = cur ^ 1;
      const bool pf = (kt + 1 < nkt);
      const int kb = kt << 6;
      if (pf) {  // issue V first (oldest), then K stage -> VMCNT(4) isolates V
        loadV((kt + 1) << 6);
        stageK((kt + 1) << 6, nxt);
      }

      // ---- QK^T on Kt[cur] ----
      f32x4 s[4] = {};
      PRIO1();
#pragma unroll
      for (int kk = 0; kk < 4; ++kk) {
        int blk = (kk * 4 + l4) ^ l7;
#pragma unroll
        for (int n = 0; n < 4; ++n) {
          bf16x8 kf = *(const bf16x8*)(&Kt[cur][(n * 16 + l15) * 128 + blk * 8]);
          s[n] = MFMA16(qf[kk], kf, s[n]);
        }
      }
      PRIO0();

      // ---- online softmax ----
      const float sc = 0.08838834764831845f;
      bool needMask = (kb + 63) > wq0;
      float scf[4];
#pragma unroll
      for (int r = 0; r < 4; ++r) {
        int q = wq0 + (l4 << 2) + r;
#pragma unroll
        for (int n = 0; n < 4; ++n) {
          float v = s[n][r] * sc;
          if (needMask && (kb + n * 16 + l15) > q) v = -1e30f;
          s[n][r] = v;
        }
        float mx = fmaxf(fmaxf(s[0][r], s[1][r]), fmaxf(s[2][r], s[3][r]));
        mx = fmaxf(mx, __shfl_xor(mx, 1));
        mx = fmaxf(mx, __shfl_xor(mx, 2));
        mx = fmaxf(mx, __shfl_xor(mx, 4));
        mx = fmaxf(mx, __shfl_xor(mx, 8));
        float mn = fmaxf(mrow[r], mx);
        float sf = __expf(mrow[r] - mn);
        mrow[r] = mn;
        scf[r] = sf;
        float rs = 0.f;
#pragma unroll
        for (int n = 0; n < 4; ++n) {
          float pv = __expf(s[n][r] - mn);
          s[n][r] = pv;
          rs += pv;
        }
        rs += __shfl_xor(rs, 1);
        rs += __shfl_xor(rs, 2);
        rs += __shfl_xor(rs, 4);
        rs += __shfl_xor(rs, 8);
        lrow[r] = lrow[r] * sf + rs;
      }

      // ---- V(t+1): V loads certified (oldest 4), K(t+1) still in flight ----
      if (pf) {
        VMCNT(4);
        writeV(nxt);
      }

      // ---- rescale + P -> Pw ----
#pragma unroll
      for (int nd = 0; nd < 8; ++nd)
#pragma unroll
        for (int r = 0; r < 4; ++r)
          acc[nd][r] *= scf[r];
#pragma unroll
      for (int n = 0; n < 4; ++n) {
        int cb8 = n * 2 + (l15 >> 3);
#pragma unroll
        for (int r = 0; r < 4; ++r) {
          int row = (l4 << 2) + r;
          Pw[w][row * 64 + ((cb8 ^ (row & 7)) << 3) + l7] = (bf16_t)s[n][r];
        }
      }

      // ---- PV on Vt[cur] ----
      PRIO1();
#pragma unroll
      for (int kk2 = 0; kk2 < 2; ++kk2) {
        bf16x8 pa = *(const bf16x8*)(&Pw[w][l15 * 64 + (((kk2 * 4 + l4) ^ l7) << 3)]);
#pragma unroll
        for (int nd = 0; nd < 8; ++nd) {
          int d = nd * 16 + l15;
          int swzv = (kk2 * 4 + l4) ^ ((d ^ (d >> 3)) & 7);
          bf16x8 bv = *(const bf16x8*)(&Vt[cur][d * 64 + swzv * 8]);
          acc[nd] = MFMA16(pa, bv, acc[nd]);
        }
      }
      PRIO0();

      LGKM0();   // all ds_writes/reads drained
      VMCNT(0);  // K(t+1) staged (issued before QK -> latency hidden)
      BAR();
    }

    // ---- epilogue ----
#pragma unroll
    for (int r = 0; r < 4; ++r) {
      float inv = 1.0f / lrow[r];
      size_t ro = (size_t)(b * 2048 + wq0 + (l4 << 2) + r) * 2048 + h * 128;
#pragma unroll
      for (int nd = 0; nd < 8; ++nd)
        att[ro + nd * 16 + l15] = (bf16_t)(acc[nd][r] * inv);
    }
  }
}

// ---------------- launch ----------------
extern "C" void kernel_launch(void* const* d_in, const int* in_sizes, int n_in,
                              void* d_out, int out_size, void* d_ws, size_t ws_size,
                              hipStream_t stream) {
  (void)in_sizes; (void)n_in; (void)out_size; (void)ws_size;
  const float* x = (const float*)d_in[0];
  const float* w_attn = (const float*)d_in[1];
  const float* b_attn = (const float*)d_in[2];
  const float* w_proj = (const float*)d_in[3];
  const float* b_proj = (const float*)d_in[4];
  float* out = (float*)d_out;

  char* ws = (char*)d_ws;
  bf16_t* xb  = (bf16_t*)(ws);
  bf16_t* wab = (bf16_t*)(ws + 16777216);
  bf16_t* wpb = (bf16_t*)(ws + 41943040);
  bf16_t* qkv = (bf16_t*)(ws + 50331648);
  bf16_t* att = xb;  // xb dead after GEMM1

  // fused conversions: 3,145,728 vec8 -> 12288 blocks
  cvt_all<<<12288, 256, 0, stream>>>(x, w_attn, w_proj, xb, wab, wpb);

  // qkv = x @ w_attn^T + b_attn -> bf16 [4096, 6144]  (r9 persistent, 512 blocks)
  gemm_w128p<1><<<512, 256, 0, stream>>>(xb, wab, b_attn, qkv, 4096, 6144, 2048);

  // causal flash attention -> att bf16 [4096, 2048]  (double-buffered K/V)
  attn_fwd<<<512, 256, 0, stream>>>(qkv, att);

  // out = att @ w_proj^T + b_proj -> f32 [4096, 2048]  (256 tiles, 1 exact round)
  gemm_w128p<0><<<256, 256, 0, stream>>>(att, wpb, b_proj, out, 4096, 2048, 2048);
}